// Round 1
// 1292.856 us; speedup vs baseline: 1.1066x; 1.1066x over previous
//
#include <hip/hip_runtime.h>
#include <math.h>

#define NR 10
#define CH 7
#define HID 128
#define NH 4
#define NL 3
#define TOK_FEATS (NR * HID)   // 1280
#define NTOK 16384

__device__ __forceinline__ float gelu_exact(float x) {
    return 0.5f * x * (1.0f + erff(x * 0.70710678118654752f));
}

// wave-uniform broadcast via readlane (VALU/scalar, keeps the LDS pipe free)
__device__ __forceinline__ float rlane(float v, int lane) {
    return __int_as_float(__builtin_amdgcn_readlane(__float_as_int(v), lane));
}

// adjacency bitmasks: bit j of kAdj[i] == adj[i][j] (incl self loops)
__device__ __constant__ unsigned short kAdj[NR] = {
    0x01F, 0x0A7, 0x08F, 0x00D, 0x031, 0x072, 0x260, 0x186, 0x180, 0x240
};

// R3 restructure: 2 waves per token. Each lane owns 4 cols per head
// (acc[10][4] = 40 VGPRs) instead of 8 (80 VGPRs), eliminating the scratch
// spill that R2's 64-VGPR clamp forced (74MB fetch / 277MB write vs ~11/168
// ideal). Wave w of a token owns within-head cols m*8 + w*4 .. +3.
__global__ void __launch_bounds__(256, 4)
brain_graph_kernel(const float* __restrict__ x,
                   const float* __restrict__ W_enc,
                   const float* __restrict__ b_enc,
                   const float* __restrict__ g_enc,
                   const float* __restrict__ beta_enc,
                   const float* __restrict__ W_gat,
                   const float* __restrict__ att_src,
                   const float* __restrict__ att_dst,
                   const float* __restrict__ b_gat,
                   float* __restrict__ out_gf,
                   float* __restrict__ out_enc) {
    const int wid  = threadIdx.x >> 6;   // 0..3
    const int tk   = wid >> 1;           // token slot in block (0..1)
    const int w    = wid & 1;            // which column-half of the token
    const int lane = threadIdx.x & 63;
    const int token = blockIdx.x * 2 + tk;

    __shared__ float s_nodes_all[2][TOK_FEATS];     // 10240 B
    __shared__ float s_asd_all[2][NR * 16];         // 1280 B [n][sd2][h4][w2]
    __shared__ float s_alpha_all[2][NR * NR * 4];   // 3200 B [(i*10+j)*4+h]
    float* s_nodes = s_nodes_all[tk];
    float* s_asd   = s_asd_all[tk];
    float* s_alpha = s_alpha_all[tk];

    // ============ encoder: wave w handles regions [5w, 5w+5) ============
    // (full 128-col LN stays wave-local: no cross-wave reduction needed)
    const float xv0 = x[(size_t)token * (NR * CH) + lane];
    const float xv1 = (lane < NR * CH - 64) ? x[(size_t)token * (NR * CH) + 64 + lane] : 0.f;
    {
        const int d0 = lane, d1 = lane + 64;
        #pragma unroll
        for (int rr = 0; rr < 5; ++rr) {
            const int r = 5 * w + rr;
            float a0 = b_enc[r * HID + d0];
            float a1 = b_enc[r * HID + d1];
            #pragma unroll
            for (int cc = 0; cc < CH; ++cc) {
                const int idx = r * CH + cc;
                const float xs = (idx < 64) ? rlane(xv0, idx) : rlane(xv1, idx - 64);
                a0 = fmaf(xs, W_enc[idx * HID + d0], a0);
                a1 = fmaf(xs, W_enc[idx * HID + d1], a1);
            }
            float s = a0 + a1, sq = a0 * a0 + a1 * a1;
            #pragma unroll
            for (int off = 32; off > 0; off >>= 1) {
                s  += __shfl_xor(s, off);
                sq += __shfl_xor(sq, off);
            }
            const float mu = s * (1.0f / 128.0f);
            const float rstd = rsqrtf(sq * (1.0f / 128.0f) - mu * mu + 1e-5f);
            const float e0 = gelu_exact((a0 - mu) * rstd * g_enc[r * HID + d0] + beta_enc[r * HID + d0]);
            const float e1 = gelu_exact((a1 - mu) * rstd * g_enc[r * HID + d1] + beta_enc[r * HID + d1]);
            s_nodes[r * HID + d0] = e0;
            s_nodes[r * HID + d1] = e1;
            out_enc[(size_t)token * TOK_FEATS + r * HID + d0] = e0;
            out_enc[(size_t)token * TOK_FEATS + r * HID + d1] = e1;
        }
    }
    __syncthreads();

    const int hl = lane >> 4;          // head owning this lane's cols
    const int m  = lane & 15;
    const int ev = m * 8 + w * 4;      // within-head col base (4 cols)
    const int c  = hl * HID + ev;      // flat col in [0,512)

    // ============ GAT layers ============
    for (int l = 0; l < NL; ++l) {
        // nodes -> distributed regs (readlane broadcast source)
        float nd0[NR], nd1[NR];
        #pragma unroll
        for (int n = 0; n < NR; ++n) {
            nd0[n] = s_nodes[n * HID + lane];
            nd1[n] = s_nodes[n * HID + 64 + lane];
        }

        // phase 1: hh[n][c..c+3] for all 10 n, in regs (40 acc VGPRs)
        float acc[NR][4];
        #pragma unroll
        for (int n = 0; n < NR; ++n) {
            acc[n][0] = acc[n][1] = acc[n][2] = acc[n][3] = 0.f;
        }

        const float* wp = W_gat + (size_t)l * HID * 512 + c;
        #pragma unroll
        for (int half = 0; half < 2; ++half) {
            #pragma unroll 4
            for (int dd = 0; dd < 64; ++dd) {
                const float4 wv = *(const float4*)wp;
                wp += 512;
                #pragma unroll
                for (int n = 0; n < NR; ++n) {
                    const float sv = rlane(half ? nd1[n] : nd0[n], dd);
                    acc[n][0] = fmaf(sv, wv.x, acc[n][0]);
                    acc[n][1] = fmaf(sv, wv.y, acc[n][1]);
                    acc[n][2] = fmaf(sv, wv.z, acc[n][2]);
                    acc[n][3] = fmaf(sv, wv.w, acc[n][3]);
                }
            }
        }

        // phase 2: a_src/a_dst partials (4 cols/lane), 16-lane butterfly
        // covers this wave's 64 cols/head; halves summed at softmax read.
        {
            const float* ap = att_src + l * (NH * HID) + hl * HID + ev;
            const float* dp = att_dst + l * (NH * HID) + hl * HID + ev;
            const float4 A = *(const float4*)ap;
            const float4 D = *(const float4*)dp;
            #pragma unroll
            for (int n = 0; n < NR; ++n) {
                float ps = acc[n][0] * A.x;
                float pd = acc[n][0] * D.x;
                ps = fmaf(acc[n][1], A.y, ps); pd = fmaf(acc[n][1], D.y, pd);
                ps = fmaf(acc[n][2], A.z, ps); pd = fmaf(acc[n][2], D.z, pd);
                ps = fmaf(acc[n][3], A.w, ps); pd = fmaf(acc[n][3], D.w, pd);
                #pragma unroll
                for (int off = 1; off < 16; off <<= 1) {
                    ps += __shfl_xor(ps, off);
                    pd += __shfl_xor(pd, off);
                }
                if (m == 0) {
                    s_asd[n * 16 + hl * 2 + w]     = ps;
                    s_asd[n * 16 + 8 + hl * 2 + w] = pd;
                }
            }
        }
        __syncthreads();

        // phase 3: masked leaky-relu softmax (w==0 wave, lanes 0..39)
        if (w == 0 && lane < NR * NH) {
            const int i = lane >> 2, h = lane & 3;
            const unsigned mask = kAdj[i];
            const float adv = s_asd[i * 16 + 8 + h * 2] + s_asd[i * 16 + 8 + h * 2 + 1];
            float lg[NR];
            float mx = -1e30f;
            #pragma unroll
            for (int j = 0; j < NR; ++j) {
                float v = adv + s_asd[j * 16 + h * 2] + s_asd[j * 16 + h * 2 + 1];
                v = (v > 0.f) ? v : 0.2f * v;
                v = ((mask >> j) & 1u) ? v : -1e9f;
                lg[j] = v;
                mx = fmaxf(mx, v);
            }
            float ssum = 0.f;
            #pragma unroll
            for (int j = 0; j < NR; ++j) {
                const float e = __expf(lg[j] - mx);
                lg[j] = e;
                ssum += e;
            }
            const float inv = 1.0f / ssum;
            #pragma unroll
            for (int j = 0; j < NR; ++j) s_alpha[(i * NR + j) * 4 + h] = lg[j] * inv;
        }
        __syncthreads();

        // phase 4: per-head partial aggregate, butterfly over heads (^16,^32),
        // mean + bias + GELU + residual. Lane reads/writes only its own 16B
        // slot of s_nodes -> no cross-wave hazard inside the phase.
        const float* bg = b_gat + l * HID;
        const float4 bgv = *(const float4*)(bg + ev);
        #pragma unroll
        for (int i = 0; i < NR; ++i) {
            float o0 = 0.f, o1 = 0.f, o2 = 0.f, o3 = 0.f;
            #pragma unroll
            for (int j = 0; j < NR; ++j) {
                const float a = s_alpha[(i * NR + j) * 4 + hl];
                o0 = fmaf(a, acc[j][0], o0);
                o1 = fmaf(a, acc[j][1], o1);
                o2 = fmaf(a, acc[j][2], o2);
                o3 = fmaf(a, acc[j][3], o3);
            }
            o0 += __shfl_xor(o0, 16); o0 += __shfl_xor(o0, 32);
            o1 += __shfl_xor(o1, 16); o1 += __shfl_xor(o1, 32);
            o2 += __shfl_xor(o2, 16); o2 += __shfl_xor(o2, 32);
            o3 += __shfl_xor(o3, 16); o3 += __shfl_xor(o3, 32);
            const float4 res = *(const float4*)&s_nodes[i * HID + ev];
            float4 nv;
            nv.x = gelu_exact(o0 * 0.25f + bgv.x) + res.x;
            nv.y = gelu_exact(o1 * 0.25f + bgv.y) + res.y;
            nv.z = gelu_exact(o2 * 0.25f + bgv.z) + res.z;
            nv.w = gelu_exact(o3 * 0.25f + bgv.w) + res.w;
            if (hl == 0) {
                *(float4*)&s_nodes[i * HID + ev] = nv;
                if (l == NL - 1)
                    *(float4*)&out_gf[(size_t)token * TOK_FEATS + i * HID + ev] = nv;
            }
        }
        __syncthreads();
    }
}

extern "C" void kernel_launch(void* const* d_in, const int* in_sizes, int n_in,
                              void* d_out, int out_size, void* d_ws, size_t ws_size,
                              hipStream_t stream) {
    const float* x        = (const float*)d_in[0];
    const float* W_enc    = (const float*)d_in[1];
    const float* b_enc    = (const float*)d_in[2];
    const float* g_enc    = (const float*)d_in[3];
    const float* beta_enc = (const float*)d_in[4];
    const float* W_gat    = (const float*)d_in[5];
    const float* att_src  = (const float*)d_in[6];
    const float* att_dst  = (const float*)d_in[7];
    const float* b_gat    = (const float*)d_in[8];

    float* out_gf  = (float*)d_out;
    float* out_enc = (float*)d_out + (size_t)NTOK * TOK_FEATS;

    brain_graph_kernel<<<NTOK / 2, 256, 0, stream>>>(
        x, W_enc, b_enc, g_enc, beta_enc, W_gat, att_src, att_dst, b_gat,
        out_gf, out_enc);
}

// Round 2
// 571.214 us; speedup vs baseline: 2.5046x; 2.2633x over previous
//
#include <hip/hip_runtime.h>
#include <math.h>

#define NR 10
#define CH 7
#define HID 128
#define NH 4
#define NL 3
#define TOK_FEATS (NR * HID)   // 1280
#define NTOK 16384
#define G 4                    // tokens per block (1 wave each)
#define MROWS (G * NR)         // 40 real A-rows
#define SNSTR 132              // padded fp32 row stride for s_nodes

// LDS layout (bytes): all dynamic (75136 B total -> 2 blocks/CU)
#define SN_OFF   0             // float [40][132]        = 21120  (nodes, residual)
#define SA_OFF   21120         // f16   [48][128] swz    = 12288  (A: nodes-f16 / mix chunk)
#define SW_OFF   33408         // f16   [128][128] swz   = 32768  (B: Wcat chunk, col-major)
#define ASD_OFF  66176         // float [40][8]          = 1280   (a_src|a_dst)
#define SAL_OFF  67456         // float [4][4][10][12]   = 7680   (alpha, 0.25-folded)
#define SMEM_BYTES 75136

typedef _Float16 f16;
typedef _Float16 half8 __attribute__((ext_vector_type(8)));
typedef float f32x4 __attribute__((ext_vector_type(4)));

__device__ __forceinline__ float gelu_exact(float x) {
    return 0.5f * x * (1.0f + erff(x * 0.70710678118654752f));
}
__device__ __forceinline__ float rlane(float v, int lane) {
    return __int_as_float(__builtin_amdgcn_readlane(__float_as_int(v), lane));
}
__device__ __forceinline__ half8 ldfrag(const char* base, int rc, int kByte) {
    // frag read: 16B at (rc*256 + kByte), XOR-swizzled to kill the 256B-stride bank conflict
    return *(const half8*)(base + ((((rc) << 8) + (kByte)) ^ (((rc) & 7) << 4)));
}
__device__ __forceinline__ void stA16(char* sA, int row, int k, float v) {
    *(f16*)(sA + ((((row) << 8) + ((k) << 1)) ^ (((row) & 7) << 4))) = (f16)v;
}
__device__ __forceinline__ half8 h8cast(uint4 u) { return __builtin_bit_cast(half8, u); }
__device__ __forceinline__ f32x4 mfma16(half8 a, half8 b, f32x4 c) {
    return __builtin_amdgcn_mfma_f32_16x16x32_f16(a, b, c, 0, 0, 0);
}

// adjacency bitmasks: bit j of kAdj[i] == adj[i][j] (incl self loops)
__device__ __constant__ unsigned short kAdj[NR] = {
    0x01F, 0x0A7, 0x08F, 0x00D, 0x031, 0x072, 0x260, 0x186, 0x180, 0x240
};

// ---------------- prep: W_gat -> Wcat_T fp16 (chunk-major, col-major within chunk)
//                  + U = W @ att_{src,dst} fp16 -------------------------------------
// Wcat_T layout: [l][h][col e][k d] f16  (so B-frag reads are contiguous 16B)
// U_T layout:    [l][c(16, 8 used)][d] f16 ; c<4: src h=c, c in 4..7: dst h=c-4
__global__ void prep_kernel(const float* __restrict__ W_gat,
                            const float* __restrict__ att_src,
                            const float* __restrict__ att_dst,
                            f16* __restrict__ ws) {
    const int NW = NL * NH * HID * HID;          // 196608
    int t = blockIdx.x * 256 + threadIdx.x;
    if (t < NW) {
        int kk = t & 127, col = (t >> 7) & 127, h = (t >> 14) & 3, l = t >> 16;
        ws[t] = (f16)W_gat[((l * HID + kk) * NH + h) * HID + col];
    } else if (t < NW + NL * 16 * HID) {
        int o = t - NW;
        int d = o & 127, c = (o >> 7) & 15, l = o >> 11;
        float v = 0.f;
        if (c < 8) {
            int h = c & 3;
            const float* att = ((c < 4) ? att_src : att_dst) + (l * NH + h) * HID;
            const float* wr  = W_gat + ((l * HID + d) * NH + h) * HID;
            #pragma unroll 4
            for (int e = 0; e < HID; ++e) v = fmaf(wr[e], att[e], v);
        }
        ws[t] = (f16)v;
    }
}

// ---------------- main kernel: 4 tokens/block, 4 waves, MFMA GAT ----------------
__global__ void __launch_bounds__(256, 2)
brain_graph_kernel(const float* __restrict__ x,
                   const float* __restrict__ W_enc,
                   const float* __restrict__ b_enc,
                   const float* __restrict__ g_enc,
                   const float* __restrict__ beta_enc,
                   const float* __restrict__ b_gat,
                   const f16* __restrict__ wq,
                   float* __restrict__ out_gf,
                   float* __restrict__ out_enc) {
    extern __shared__ __align__(16) char smem[];
    float* sN   = (float*)(smem + SN_OFF);
    char*  sA   = smem + SA_OFF;
    char*  sW   = smem + SW_OFF;
    float* sasd = (float*)(smem + ASD_OFF);
    float* sAL  = (float*)(smem + SAL_OFF);

    const int w     = threadIdx.x >> 6;
    const int lane  = threadIdx.x & 63;
    const int token = blockIdx.x * G + w;
    const int rb    = w * NR;          // this wave's A-row base
    const int cl    = lane & 15;       // frag row/col-low
    const int kg    = lane >> 4;       // frag k-group

    // ============ encoder: Linear(7->128) + LN + GELU (1 wave / token) ============
    const float xv0 = x[(size_t)token * (NR * CH) + lane];
    const float xv1 = (lane < NR * CH - 64) ? x[(size_t)token * (NR * CH) + 64 + lane] : 0.f;
    {
        const int d0 = lane, d1 = lane + 64;
        #pragma unroll
        for (int r = 0; r < NR; ++r) {
            float a0 = b_enc[r * HID + d0];
            float a1 = b_enc[r * HID + d1];
            #pragma unroll
            for (int c = 0; c < CH; ++c) {
                const int idx = r * CH + c;
                const float xs = (idx < 64) ? rlane(xv0, idx) : rlane(xv1, idx - 64);
                a0 = fmaf(xs, W_enc[idx * HID + d0], a0);
                a1 = fmaf(xs, W_enc[idx * HID + d1], a1);
            }
            float s = a0 + a1, sq = a0 * a0 + a1 * a1;
            #pragma unroll
            for (int off = 32; off > 0; off >>= 1) {
                s  += __shfl_xor(s, off);
                sq += __shfl_xor(sq, off);
            }
            const float mu = s * (1.0f / 128.0f);
            const float rstd = rsqrtf(sq * (1.0f / 128.0f) - mu * mu + 1e-5f);
            const float e0 = gelu_exact((a0 - mu) * rstd * g_enc[r * HID + d0] + beta_enc[r * HID + d0]);
            const float e1 = gelu_exact((a1 - mu) * rstd * g_enc[r * HID + d1] + beta_enc[r * HID + d1]);
            sN[(rb + r) * SNSTR + d0] = e0;
            sN[(rb + r) * SNSTR + d1] = e1;
            out_enc[(size_t)token * TOK_FEATS + r * HID + d0] = e0;
            out_enc[(size_t)token * TOK_FEATS + r * HID + d1] = e1;
        }
    }
    // zero A pad rows 40..47 once (stay zero forever; swizzle-agnostic since zeros)
    if (threadIdx.x < 128) ((uint4*)(sA + MROWS * 256))[threadIdx.x] = make_uint4(0, 0, 0, 0);
    __syncthreads();

    const char* Wq = (const char*)wq;                                  // [l][h] 32KB chunks
    const char* Uq = (const char*)(wq + NL * NH * HID * HID);          // U_T

    for (int l = 0; l < NL; ++l) {
        // ---- step 1: reload nodes to regs; write nodes-f16 into A (for a_sd MFMA) ----
        float nd0[NR], nd1[NR];
        #pragma unroll
        for (int n = 0; n < NR; ++n) {
            nd0[n] = sN[(rb + n) * SNSTR + lane];
            nd1[n] = sN[(rb + n) * SNSTR + 64 + lane];
        }
        #pragma unroll
        for (int n = 0; n < NR; ++n) {
            stA16(sA, rb + n, lane, nd0[n]);
            stA16(sA, rb + n, 64 + lane, nd1[n]);
        }
        __syncthreads();

        // ---- step 2: stage W chunk h=0 (reg-staged, swizzled) + a_sd MFMA ----
        uint4 stg[8];
        {
            const char* src = Wq + (size_t)(l * 4 + 0) * 32768;
            #pragma unroll
            for (int r = 0; r < 8; ++r) {
                int q = (r * 256 + threadIdx.x) * 16;
                stg[r] = *(const uint4*)(src + (q ^ (((q >> 8) & 7) << 4)));
            }
        }
        if (w < 3) {  // waves 0..2 own M-tiles 0..2 of the 48-row A
            const char* ub = Uq + (((l * 16 + cl) * 128 + kg * 8) << 1);
            uint4 u0 = *(const uint4*)(ub);
            uint4 u1 = *(const uint4*)(ub + 64);
            uint4 u2 = *(const uint4*)(ub + 128);
            uint4 u3 = *(const uint4*)(ub + 192);
            const int row = w * 16 + cl;
            f32x4 cu = {0.f, 0.f, 0.f, 0.f};
            cu = mfma16(ldfrag(sA, row, 0 * 64 + kg * 16), h8cast(u0), cu);
            cu = mfma16(ldfrag(sA, row, 1 * 64 + kg * 16), h8cast(u1), cu);
            cu = mfma16(ldfrag(sA, row, 2 * 64 + kg * 16), h8cast(u2), cu);
            cu = mfma16(ldfrag(sA, row, 3 * 64 + kg * 16), h8cast(u3), cu);
            if (cl < 8) {
                #pragma unroll
                for (int r = 0; r < 4; ++r) {
                    int rr = w * 16 + kg * 4 + r;
                    if (rr < MROWS) sasd[rr * 8 + cl] = cu[r];
                }
            }
        }
        #pragma unroll
        for (int r = 0; r < 8; ++r) {
            int q = (r * 256 + threadIdx.x) * 16;
            *(uint4*)(sW + q) = stg[r];
        }
        __syncthreads();

        // ---- step 3: masked leaky-relu softmax (lanes 0..39, own token); fold 0.25 ----
        if (lane < NR * NH) {
            const int i = lane >> 2, h = lane & 3;
            const unsigned mask = kAdj[i];
            const float adv = sasd[(rb + i) * 8 + 4 + h];
            float lg[NR];
            float mx = -1e30f;
            #pragma unroll
            for (int j = 0; j < NR; ++j) {
                float v = adv + sasd[(rb + j) * 8 + h];
                v = (v > 0.f) ? v : 0.2f * v;
                v = ((mask >> j) & 1u) ? v : -1e9f;
                lg[j] = v;
                mx = fmaxf(mx, v);
            }
            float ssum = 0.f;
            #pragma unroll
            for (int j = 0; j < NR; ++j) {
                const float e = __expf(lg[j] - mx);
                lg[j] = e;
                ssum += e;
            }
            const float inv = 0.25f / ssum;   // fold mean-over-heads
            const int base = ((w * 4 + h) * 10 + i) * 12;
            #pragma unroll
            for (int j = 0; j < NR; ++j) sAL[base + j] = lg[j] * inv;
        }
        __syncthreads();

        // ---- step 4: 4 K-chunks: mix_h (VALU) -> A ; staged W_h ; MFMA accumulate ----
        f32x4 C[3][2] = {};
        #pragma unroll
        for (int h = 0; h < 4; ++h) {
            if (h > 0) {  // issue W_h loads early; ds_write after mix (latency hidden)
                const char* src = Wq + (size_t)(l * 4 + h) * 32768;
                #pragma unroll
                for (int r = 0; r < 8; ++r) {
                    int q = (r * 256 + threadIdx.x) * 16;
                    stg[r] = *(const uint4*)(src + (q ^ (((q >> 8) & 7) << 4)));
                }
            }
            // mix[i, h, d] = sum_j alpha[i,j,h]*nodes[j,d], d = lane & 64+lane
            #pragma unroll
            for (int i = 0; i < NR; ++i) {
                const float4* ap = (const float4*)&sAL[((w * 4 + h) * 10 + i) * 12];
                const float4 A0 = ap[0], A1 = ap[1], A2 = ap[2];  // A2.z/.w unused
                float m0 = A0.x * nd0[0], m1 = A0.x * nd1[0];
                m0 = fmaf(A0.y, nd0[1], m0); m1 = fmaf(A0.y, nd1[1], m1);
                m0 = fmaf(A0.z, nd0[2], m0); m1 = fmaf(A0.z, nd1[2], m1);
                m0 = fmaf(A0.w, nd0[3], m0); m1 = fmaf(A0.w, nd1[3], m1);
                m0 = fmaf(A1.x, nd0[4], m0); m1 = fmaf(A1.x, nd1[4], m1);
                m0 = fmaf(A1.y, nd0[5], m0); m1 = fmaf(A1.y, nd1[5], m1);
                m0 = fmaf(A1.z, nd0[6], m0); m1 = fmaf(A1.z, nd1[6], m1);
                m0 = fmaf(A1.w, nd0[7], m0); m1 = fmaf(A1.w, nd1[7], m1);
                m0 = fmaf(A2.x, nd0[8], m0); m1 = fmaf(A2.x, nd1[8], m1);
                m0 = fmaf(A2.y, nd0[9], m0); m1 = fmaf(A2.y, nd1[9], m1);
                stA16(sA, rb + i, lane, m0);
                stA16(sA, rb + i, 64 + lane, m1);
            }
            if (h > 0) {
                #pragma unroll
                for (int r = 0; r < 8; ++r) {
                    int q = (r * 256 + threadIdx.x) * 16;
                    *(uint4*)(sW + q) = stg[r];
                }
            }
            __syncthreads();
            // MFMA: C[mt][nt] += A_chunk @ W_chunk ; wave owns N-cols [w*32, w*32+32)
            #pragma unroll
            for (int ks = 0; ks < 4; ++ks) {
                const int kB = ks * 64 + kg * 16;
                half8 b0 = ldfrag(sW, w * 32 + cl, kB);
                half8 b1 = ldfrag(sW, w * 32 + 16 + cl, kB);
                half8 a0 = ldfrag(sA, 0 * 16 + cl, kB);
                half8 a1 = ldfrag(sA, 1 * 16 + cl, kB);
                half8 a2 = ldfrag(sA, 2 * 16 + cl, kB);
                C[0][0] = mfma16(a0, b0, C[0][0]);
                C[0][1] = mfma16(a0, b1, C[0][1]);
                C[1][0] = mfma16(a1, b0, C[1][0]);
                C[1][1] = mfma16(a1, b1, C[1][1]);
                C[2][0] = mfma16(a2, b0, C[2][0]);
                C[2][1] = mfma16(a2, b1, C[2][1]);
            }
            __syncthreads();
        }

        // ---- step 5: epilogue: +bias, GELU, +residual; update sN (+ final store) ----
        const float bg0 = b_gat[l * HID + w * 32 + cl];
        const float bg1 = b_gat[l * HID + w * 32 + 16 + cl];
        #pragma unroll
        for (int mt = 0; mt < 3; ++mt) {
            #pragma unroll
            for (int nt = 0; nt < 2; ++nt) {
                const f32x4 cv = C[mt][nt];
                const int col = w * 32 + nt * 16 + cl;
                const float bg = nt ? bg1 : bg0;
                #pragma unroll
                for (int r = 0; r < 4; ++r) {
                    const int row = mt * 16 + kg * 4 + r;
                    if (row < MROWS) {
                        const float v = gelu_exact(cv[r] + bg) + sN[row * SNSTR + col];
                        sN[row * SNSTR + col] = v;
                        if (l == NL - 1) {
                            const int tok = (row * 13) >> 7;   // row/10 for row<40
                            const int n = row - tok * 10;
                            out_gf[(size_t)(blockIdx.x * G + tok) * TOK_FEATS + n * HID + col] = v;
                        }
                    }
                }
            }
        }
        __syncthreads();
    }
}

extern "C" void kernel_launch(void* const* d_in, const int* in_sizes, int n_in,
                              void* d_out, int out_size, void* d_ws, size_t ws_size,
                              hipStream_t stream) {
    const float* x        = (const float*)d_in[0];
    const float* W_enc    = (const float*)d_in[1];
    const float* b_enc    = (const float*)d_in[2];
    const float* g_enc    = (const float*)d_in[3];
    const float* beta_enc = (const float*)d_in[4];
    const float* W_gat    = (const float*)d_in[5];
    const float* att_src  = (const float*)d_in[6];
    const float* att_dst  = (const float*)d_in[7];
    const float* b_gat    = (const float*)d_in[8];

    float* out_gf  = (float*)d_out;
    float* out_enc = (float*)d_out + (size_t)NTOK * TOK_FEATS;
    f16* wsw = (f16*)d_ws;   // 405504 B used

    prep_kernel<<<792, 256, 0, stream>>>(W_gat, att_src, att_dst, wsw);

    (void)hipFuncSetAttribute((const void*)brain_graph_kernel,
                              hipFuncAttributeMaxDynamicSharedMemorySize, SMEM_BYTES);
    brain_graph_kernel<<<NTOK / G, 256, SMEM_BYTES, stream>>>(
        x, W_enc, b_enc, g_enc, beta_enc, b_gat, wsw, out_gf, out_enc);
}

// Round 3
// 476.433 us; speedup vs baseline: 3.0029x; 1.1989x over previous
//
#include <hip/hip_runtime.h>
#include <math.h>

#define NR 10
#define CH 7
#define HID 128
#define NH 4
#define NL 3
#define TOK_FEATS (NR * HID)   // 1280
#define NTOK 16384
#define G 8                    // tokens per block (1 wave each)
#define MROWS (G * NR)         // 80 real A-rows = exactly 5 M-tiles
#define SNSTR 130              // padded fp32 row stride for s_nodes

// LDS layout (bytes): 80000 total -> 2 blocks/CU (16 waves/CU, 50% occ)
#define SN_OFF   0             // float [80][130]        = 41600  (nodes fp32, residual)
#define SA_OFF   41600         // f16   [80][128] swz    = 20480  (A: nodes-f16 / mix chunk)
#define ASD_OFF  62080         // float [80][8]          = 2560   (a_src|a_dst)
#define SAL_OFF  64640         // float [8][4][10][12]   = 15360  (alpha, 0.25-folded)
#define SMEM_BYTES 80000

typedef _Float16 f16;
typedef _Float16 half8 __attribute__((ext_vector_type(8)));
typedef float f32x4 __attribute__((ext_vector_type(4)));

__device__ __forceinline__ float gelu_exact(float x) {
    return 0.5f * x * (1.0f + erff(x * 0.70710678118654752f));
}
__device__ __forceinline__ float rlane(float v, int lane) {
    return __int_as_float(__builtin_amdgcn_readlane(__float_as_int(v), lane));
}
// frag read: 16B at (rc*256 + kByte), XOR-swizzled (G4: kills 256B-stride conflicts)
__device__ __forceinline__ half8 ldfrag(const char* base, int rc, int kByte) {
    return *(const half8*)(base + ((((rc) << 8) + (kByte)) ^ (((rc) & 7) << 4)));
}
// packed f16-pair write: lane owns cols (2*lane, 2*lane+1) of row -> one b32
__device__ __forceinline__ void stPair(char* sA, int row, int lane, float a, float b) {
    const unsigned short ha = __builtin_bit_cast(unsigned short, (f16)a);
    const unsigned short hb = __builtin_bit_cast(unsigned short, (f16)b);
    const unsigned u = ((unsigned)hb << 16) | ha;
    *(unsigned*)(sA + ((((row) << 8) + ((lane) << 2)) ^ (((row) & 7) << 4))) = u;
}
__device__ __forceinline__ half8 h8cast(uint4 u) { return __builtin_bit_cast(half8, u); }
__device__ __forceinline__ f32x4 mfma16(half8 a, half8 b, f32x4 c) {
    return __builtin_amdgcn_mfma_f32_16x16x32_f16(a, b, c, 0, 0, 0);
}

// adjacency bitmasks: bit j of kAdj[i] == adj[i][j] (incl self loops)
__device__ __constant__ unsigned short kAdj[NR] = {
    0x01F, 0x0A7, 0x08F, 0x00D, 0x031, 0x072, 0x260, 0x186, 0x180, 0x240
};

// ---------------- prep: W_gat -> Wcat_T fp16 ([l][h][col e][k d], so B-frags are
// contiguous 16B) + U = W @ att_{src,dst} fp16 ([l][c 16][d]; c<4 src, 4..7 dst) ----
__global__ void prep_kernel(const float* __restrict__ W_gat,
                            const float* __restrict__ att_src,
                            const float* __restrict__ att_dst,
                            f16* __restrict__ ws) {
    const int NW = NL * NH * HID * HID;          // 196608
    int t = blockIdx.x * 256 + threadIdx.x;
    if (t < NW) {
        int kk = t & 127, col = (t >> 7) & 127, h = (t >> 14) & 3, l = t >> 16;
        ws[t] = (f16)W_gat[((l * HID + kk) * NH + h) * HID + col];
    } else if (t < NW + NL * 16 * HID) {
        int o = t - NW;
        int d = o & 127, c = (o >> 7) & 15, l = o >> 11;
        float v = 0.f;
        if (c < 8) {
            int h = c & 3;
            const float* att = ((c < 4) ? att_src : att_dst) + (l * NH + h) * HID;
            const float* wr  = W_gat + ((l * HID + d) * NH + h) * HID;
            #pragma unroll 4
            for (int e = 0; e < HID; ++e) v = fmaf(wr[e], att[e], v);
        }
        ws[t] = (f16)v;
    }
}

// ---------------- main kernel: 8 tokens/block, 8 waves, MFMA GAT ----------------
__global__ void __launch_bounds__(512, 4)
brain_graph_kernel(const float* __restrict__ x,
                   const float* __restrict__ W_enc,
                   const float* __restrict__ b_enc,
                   const float* __restrict__ g_enc,
                   const float* __restrict__ beta_enc,
                   const float* __restrict__ b_gat,
                   const f16* __restrict__ wq,
                   float* __restrict__ out_gf,
                   float* __restrict__ out_enc) {
    extern __shared__ __align__(16) char smem[];
    float* sN   = (float*)(smem + SN_OFF);
    char*  sA   = smem + SA_OFF;
    float* sasd = (float*)(smem + ASD_OFF);
    float* sAL  = (float*)(smem + SAL_OFF);

    const int w     = threadIdx.x >> 6;   // wave = token slot (0..7)
    const int lane  = threadIdx.x & 63;
    const int token = blockIdx.x * G + w;
    const int rb    = w * NR;             // this wave's global A-row base
    const int cl    = lane & 15;          // frag row/col-low
    const int kg    = lane >> 4;          // frag k-group

    // ============ encoder: Linear(7->128) + LN + GELU (1 wave / token) ============
    const float xv0 = x[(size_t)token * (NR * CH) + lane];
    const float xv1 = (lane < NR * CH - 64) ? x[(size_t)token * (NR * CH) + 64 + lane] : 0.f;
    {
        const int d0 = lane, d1 = lane + 64;
        #pragma unroll
        for (int r = 0; r < NR; ++r) {
            float a0 = b_enc[r * HID + d0];
            float a1 = b_enc[r * HID + d1];
            #pragma unroll
            for (int c = 0; c < CH; ++c) {
                const int idx = r * CH + c;
                const float xs = (idx < 64) ? rlane(xv0, idx) : rlane(xv1, idx - 64);
                a0 = fmaf(xs, W_enc[idx * HID + d0], a0);
                a1 = fmaf(xs, W_enc[idx * HID + d1], a1);
            }
            float s = a0 + a1, sq = a0 * a0 + a1 * a1;
            #pragma unroll
            for (int off = 32; off > 0; off >>= 1) {
                s  += __shfl_xor(s, off);
                sq += __shfl_xor(sq, off);
            }
            const float mu = s * (1.0f / 128.0f);
            const float rstd = rsqrtf(sq * (1.0f / 128.0f) - mu * mu + 1e-5f);
            const float e0 = gelu_exact((a0 - mu) * rstd * g_enc[r * HID + d0] + beta_enc[r * HID + d0]);
            const float e1 = gelu_exact((a1 - mu) * rstd * g_enc[r * HID + d1] + beta_enc[r * HID + d1]);
            sN[(rb + r) * SNSTR + d0] = e0;
            sN[(rb + r) * SNSTR + d1] = e1;
            out_enc[(size_t)token * TOK_FEATS + r * HID + d0] = e0;
            out_enc[(size_t)token * TOK_FEATS + r * HID + d1] = e1;
        }
    }
    __syncthreads();

    const char* Wq = (const char*)wq;                                  // [l][h][e][d]
    const char* Uq = (const char*)(wq + NL * NH * HID * HID);          // U_T

    for (int l = 0; l < NL; ++l) {
        // ---- step 1: nodes -> regs (col-pairs) + packed nodes-f16 into sA ----
        float ndA[NR], ndB[NR];
        #pragma unroll
        for (int n = 0; n < NR; ++n) {
            const float2 v = *(const float2*)&sN[(rb + n) * SNSTR + 2 * lane];
            ndA[n] = v.x; ndB[n] = v.y;
            stPair(sA, rb + n, lane, v.x, v.y);
        }
        __syncthreads();

        // ---- step 2: a_sd MFMA (waves 0..4, mt=w), B = U_T straight from L2 ----
        if (w < 5) {
            const char* ub = Uq + (((l * 16 + cl) * 128 + kg * 8) << 1);
            const uint4 u0 = *(const uint4*)(ub);
            const uint4 u1 = *(const uint4*)(ub + 64);
            const uint4 u2 = *(const uint4*)(ub + 128);
            const uint4 u3 = *(const uint4*)(ub + 192);
            const int row = w * 16 + cl;
            f32x4 cu = {0.f, 0.f, 0.f, 0.f};
            cu = mfma16(ldfrag(sA, row, 0 * 64 + kg * 16), h8cast(u0), cu);
            cu = mfma16(ldfrag(sA, row, 1 * 64 + kg * 16), h8cast(u1), cu);
            cu = mfma16(ldfrag(sA, row, 2 * 64 + kg * 16), h8cast(u2), cu);
            cu = mfma16(ldfrag(sA, row, 3 * 64 + kg * 16), h8cast(u3), cu);
            if (cl < 8) {
                #pragma unroll
                for (int r = 0; r < 4; ++r)
                    sasd[(w * 16 + kg * 4 + r) * 8 + cl] = cu[r];
            }
        }
        __syncthreads();

        // ---- step 3: masked leaky-relu softmax (lanes 0..39 of each wave) ----
        if (lane < NR * NH) {
            const int i = lane >> 2, h = lane & 3;
            const unsigned mask = kAdj[i];
            const float adv = sasd[(rb + i) * 8 + 4 + h];
            float lg[NR];
            float mx = -1e30f;
            #pragma unroll
            for (int j = 0; j < NR; ++j) {
                float v = adv + sasd[(rb + j) * 8 + h];
                v = (v > 0.f) ? v : 0.2f * v;
                v = ((mask >> j) & 1u) ? v : -1e9f;
                lg[j] = v;
                mx = fmaxf(mx, v);
            }
            float ssum = 0.f;
            #pragma unroll
            for (int j = 0; j < NR; ++j) {
                const float e = __expf(lg[j] - mx);
                lg[j] = e;
                ssum += e;
            }
            const float inv = 0.25f / ssum;   // fold mean-over-heads
            const int base = ((w * 4 + h) * 10 + i) * 12;
            #pragma unroll
            for (int j = 0; j < NR; ++j) sAL[base + j] = lg[j] * inv;
        }
        __syncthreads();

        // ---- step 4: 4 K-chunks: mix_h (VALU) -> sA ; MFMA with B-frags from L2 ----
        f32x4 C[5] = {};
        #pragma unroll
        for (int h = 0; h < NH; ++h) {
            // mix[i, d] = sum_j alpha[i,j,h]*nodes[j,d]; lane owns d = 2*lane, 2*lane+1
            #pragma unroll
            for (int i = 0; i < NR; ++i) {
                const float4* ap = (const float4*)&sAL[((w * 4 + h) * 10 + i) * 12];
                const float4 A0 = ap[0], A1 = ap[1], A2 = ap[2];  // A2.z/.w unused
                float m0 = A0.x * ndA[0], m1 = A0.x * ndB[0];
                m0 = fmaf(A0.y, ndA[1], m0); m1 = fmaf(A0.y, ndB[1], m1);
                m0 = fmaf(A0.z, ndA[2], m0); m1 = fmaf(A0.z, ndB[2], m1);
                m0 = fmaf(A0.w, ndA[3], m0); m1 = fmaf(A0.w, ndB[3], m1);
                m0 = fmaf(A1.x, ndA[4], m0); m1 = fmaf(A1.x, ndB[4], m1);
                m0 = fmaf(A1.y, ndA[5], m0); m1 = fmaf(A1.y, ndB[5], m1);
                m0 = fmaf(A1.z, ndA[6], m0); m1 = fmaf(A1.z, ndB[6], m1);
                m0 = fmaf(A1.w, ndA[7], m0); m1 = fmaf(A1.w, ndB[7], m1);
                m0 = fmaf(A2.x, ndA[8], m0); m1 = fmaf(A2.x, ndB[8], m1);
                m0 = fmaf(A2.y, ndA[9], m0); m1 = fmaf(A2.y, ndB[9], m1);
                stPair(sA, rb + i, lane, m0, m1);
            }
            __syncthreads();
            // B-frags straight from L2: wave owns out-cols [w*16, w*16+16)
            const char* wb = Wq + ((size_t)((l * 4 + h) * 128 + w * 16 + cl) << 8) + kg * 16;
            const uint4 b0 = *(const uint4*)(wb);
            const uint4 b1 = *(const uint4*)(wb + 64);
            const uint4 b2 = *(const uint4*)(wb + 128);
            const uint4 b3 = *(const uint4*)(wb + 192);
            #pragma unroll
            for (int ks = 0; ks < 4; ++ks) {
                const int kB = ks * 64 + kg * 16;
                const half8 b = h8cast(ks == 0 ? b0 : ks == 1 ? b1 : ks == 2 ? b2 : b3);
                #pragma unroll
                for (int mt = 0; mt < 5; ++mt)
                    C[mt] = mfma16(ldfrag(sA, mt * 16 + cl, kB), b, C[mt]);
            }
            __syncthreads();
        }

        // ---- step 5: epilogue: +bias, GELU, +residual; update sN (+ final store) ----
        const float bg = b_gat[l * HID + w * 16 + cl];
        const int col = w * 16 + cl;
        #pragma unroll
        for (int mt = 0; mt < 5; ++mt) {
            #pragma unroll
            for (int r = 0; r < 4; ++r) {
                const int row = mt * 16 + kg * 4 + r;
                const float v = gelu_exact(C[mt][r] + bg) + sN[row * SNSTR + col];
                sN[row * SNSTR + col] = v;
                if (l == NL - 1) {
                    out_gf[(size_t)(blockIdx.x * G + row / NR) * TOK_FEATS
                           + (row % NR) * HID + col] = v;
                }
            }
        }
        __syncthreads();
    }
}

extern "C" void kernel_launch(void* const* d_in, const int* in_sizes, int n_in,
                              void* d_out, int out_size, void* d_ws, size_t ws_size,
                              hipStream_t stream) {
    const float* x        = (const float*)d_in[0];
    const float* W_enc    = (const float*)d_in[1];
    const float* b_enc    = (const float*)d_in[2];
    const float* g_enc    = (const float*)d_in[3];
    const float* beta_enc = (const float*)d_in[4];
    const float* W_gat    = (const float*)d_in[5];
    const float* att_src  = (const float*)d_in[6];
    const float* att_dst  = (const float*)d_in[7];
    const float* b_gat    = (const float*)d_in[8];

    float* out_gf  = (float*)d_out;
    float* out_enc = (float*)d_out + (size_t)NTOK * TOK_FEATS;
    f16* wsw = (f16*)d_ws;   // 405504 B used

    prep_kernel<<<792, 256, 0, stream>>>(W_gat, att_src, att_dst, wsw);

    (void)hipFuncSetAttribute((const void*)brain_graph_kernel,
                              hipFuncAttributeMaxDynamicSharedMemorySize, SMEM_BYTES);
    brain_graph_kernel<<<NTOK / G, 512, SMEM_BYTES, stream>>>(
        x, W_enc, b_enc, g_enc, beta_enc, b_gat, wsw, out_gf, out_enc);
}

// Round 4
// 438.157 us; speedup vs baseline: 3.2652x; 1.0874x over previous
//
#include <hip/hip_runtime.h>
#include <math.h>

#define NR 10
#define CH 7
#define HID 128
#define NH 4
#define NL 3
#define TOK_FEATS (NR * HID)   // 1280
#define NTOK 16384
#define G 8                    // tokens per block (1 wave each)
#define MROWS (G * NR)         // 80 real A-rows = exactly 5 M-tiles
#define SNSTR 130              // padded fp32 row stride for s_nodes

// LDS layout (bytes): 80000 total -> 2 blocks/CU (16 waves/CU, 50% occ)
#define SN_OFF   0             // float [80][130]        = 41600  (nodes fp32, residual)
#define SA_OFF   41600         // f16   [80][128] swz    = 20480  (A: nodes-f16 / mix chunk)
#define ASD_OFF  62080         // float [80][8]          = 2560   (a_src|a_dst)
#define SAL_OFF  64640         // float [8][4][10][12]   = 15360  (alpha, 0.25-folded)
#define SMEM_BYTES 80000

typedef _Float16 f16;
typedef _Float16 half8 __attribute__((ext_vector_type(8)));
typedef float f32x4 __attribute__((ext_vector_type(4)));

__device__ __forceinline__ float gelu_exact(float x) {
    return 0.5f * x * (1.0f + erff(x * 0.70710678118654752f));
}
__device__ __forceinline__ float rlane(float v, int lane) {
    return __int_as_float(__builtin_amdgcn_readlane(__float_as_int(v), lane));
}
// frag read: 16B at (rc*256 + kByte), XOR-swizzled (G4: kills 256B-stride conflicts)
__device__ __forceinline__ half8 ldfrag(const char* base, int rc, int kByte) {
    return *(const half8*)(base + ((((rc) << 8) + (kByte)) ^ (((rc) & 7) << 4)));
}
// packed f16-pair write: lane owns cols (2*lane, 2*lane+1) of row -> one b32
__device__ __forceinline__ void stPair(char* sA, int row, int lane, float a, float b) {
    const unsigned short ha = __builtin_bit_cast(unsigned short, (f16)a);
    const unsigned short hb = __builtin_bit_cast(unsigned short, (f16)b);
    const unsigned u = ((unsigned)hb << 16) | ha;
    *(unsigned*)(sA + ((((row) << 8) + ((lane) << 2)) ^ (((row) & 7) << 4))) = u;
}
__device__ __forceinline__ half8 h8cast(uint4 u) { return __builtin_bit_cast(half8, u); }
__device__ __forceinline__ f32x4 mfma16(half8 a, half8 b, f32x4 c) {
    return __builtin_amdgcn_mfma_f32_16x16x32_f16(a, b, c, 0, 0, 0);
}

// adjacency bitmasks: bit j of adj[i] == edge j->i (incl self loops)
__device__ __constant__ unsigned short kAdj[NR] = {
    0x01F, 0x0A7, 0x08F, 0x00D, 0x031, 0x072, 0x260, 0x186, 0x180, 0x240
};
// compile-time copy: fully-unrolled sparse mix (36 edges, dead FMAs fold away)
constexpr unsigned kAdjC[NR] = {
    0x01F, 0x0A7, 0x08F, 0x00D, 0x031, 0x072, 0x260, 0x186, 0x180, 0x240
};

// ---------------- prep: W_gat -> Wcat_T fp16 ([l][h][col e][k d], so B-frags are
// contiguous 16B) + U = W @ att_{src,dst} fp16 ([l][c 16][d]; c<4 src, 4..7 dst) ----
__global__ void prep_kernel(const float* __restrict__ W_gat,
                            const float* __restrict__ att_src,
                            const float* __restrict__ att_dst,
                            f16* __restrict__ ws) {
    const int NW = NL * NH * HID * HID;          // 196608
    int t = blockIdx.x * 256 + threadIdx.x;
    if (t < NW) {
        int kk = t & 127, col = (t >> 7) & 127, h = (t >> 14) & 3, l = t >> 16;
        ws[t] = (f16)W_gat[((l * HID + kk) * NH + h) * HID + col];
    } else if (t < NW + NL * 16 * HID) {
        int o = t - NW;
        int d = o & 127, c = (o >> 7) & 15, l = o >> 11;
        float v = 0.f;
        if (c < 8) {
            int h = c & 3;
            const float* att = ((c < 4) ? att_src : att_dst) + (l * NH + h) * HID;
            const float* wr  = W_gat + ((l * HID + d) * NH + h) * HID;
            #pragma unroll 4
            for (int e = 0; e < HID; ++e) v = fmaf(wr[e], att[e], v);
        }
        ws[t] = (f16)v;
    }
}

// ---------------- main kernel: 8 tokens/block, 8 waves, MFMA GAT ----------------
// waves_per_eu(4,4) pins the 128-VGPR tier: with only the min bound (R3), LLVM
// targeted 8 waves/EU -> 64 VGPRs -> 152 MiB scratch spill traffic.
__global__ void
__attribute__((amdgpu_flat_work_group_size(512, 512), amdgpu_waves_per_eu(4, 4)))
brain_graph_kernel(const float* __restrict__ x,
                   const float* __restrict__ W_enc,
                   const float* __restrict__ b_enc,
                   const float* __restrict__ g_enc,
                   const float* __restrict__ beta_enc,
                   const float* __restrict__ b_gat,
                   const f16* __restrict__ wq,
                   float* __restrict__ out_gf,
                   float* __restrict__ out_enc) {
    extern __shared__ __align__(16) char smem[];
    float* sN   = (float*)(smem + SN_OFF);
    char*  sA   = smem + SA_OFF;
    float* sasd = (float*)(smem + ASD_OFF);
    float* sAL  = (float*)(smem + SAL_OFF);

    const int w     = threadIdx.x >> 6;   // wave = token slot (0..7)
    const int lane  = threadIdx.x & 63;
    const int token = blockIdx.x * G + w;
    const int rb    = w * NR;             // this wave's global A-row base
    const int cl    = lane & 15;          // frag row/col-low
    const int kg    = lane >> 4;          // frag k-group

    // ============ encoder: Linear(7->128) + LN + GELU (1 wave / token) ============
    const float xv0 = x[(size_t)token * (NR * CH) + lane];
    const float xv1 = (lane < NR * CH - 64) ? x[(size_t)token * (NR * CH) + 64 + lane] : 0.f;
    {
        const int d0 = lane, d1 = lane + 64;
        #pragma unroll
        for (int r = 0; r < NR; ++r) {
            float a0 = b_enc[r * HID + d0];
            float a1 = b_enc[r * HID + d1];
            #pragma unroll
            for (int c = 0; c < CH; ++c) {
                const int idx = r * CH + c;
                const float xs = (idx < 64) ? rlane(xv0, idx) : rlane(xv1, idx - 64);
                a0 = fmaf(xs, W_enc[idx * HID + d0], a0);
                a1 = fmaf(xs, W_enc[idx * HID + d1], a1);
            }
            float s = a0 + a1, sq = a0 * a0 + a1 * a1;
            #pragma unroll
            for (int off = 32; off > 0; off >>= 1) {
                s  += __shfl_xor(s, off);
                sq += __shfl_xor(sq, off);
            }
            const float mu = s * (1.0f / 128.0f);
            const float rstd = rsqrtf(sq * (1.0f / 128.0f) - mu * mu + 1e-5f);
            const float e0 = gelu_exact((a0 - mu) * rstd * g_enc[r * HID + d0] + beta_enc[r * HID + d0]);
            const float e1 = gelu_exact((a1 - mu) * rstd * g_enc[r * HID + d1] + beta_enc[r * HID + d1]);
            sN[(rb + r) * SNSTR + d0] = e0;
            sN[(rb + r) * SNSTR + d1] = e1;
            out_enc[(size_t)token * TOK_FEATS + r * HID + d0] = e0;
            out_enc[(size_t)token * TOK_FEATS + r * HID + d1] = e1;
        }
    }
    __syncthreads();

    const char* Wq = (const char*)wq;                                  // [l][h][e][d]
    const char* Uq = (const char*)(wq + NL * NH * HID * HID);          // U_T

    for (int l = 0; l < NL; ++l) {
        // ---- step 1: nodes -> regs (col-pairs) + packed nodes-f16 into sA ----
        float ndA[NR], ndB[NR];
        #pragma unroll
        for (int n = 0; n < NR; ++n) {
            const float2 v = *(const float2*)&sN[(rb + n) * SNSTR + 2 * lane];
            ndA[n] = v.x; ndB[n] = v.y;
            stPair(sA, rb + n, lane, v.x, v.y);
        }
        __syncthreads();

        // ---- step 2: a_sd MFMA (waves 0..4, mt=w), B = U_T straight from L2 ----
        if (w < 5) {
            const char* ub = Uq + (((l * 16 + cl) * 128 + kg * 8) << 1);
            const uint4 u0 = *(const uint4*)(ub);
            const uint4 u1 = *(const uint4*)(ub + 64);
            const uint4 u2 = *(const uint4*)(ub + 128);
            const uint4 u3 = *(const uint4*)(ub + 192);
            const int row = w * 16 + cl;
            f32x4 cu = {0.f, 0.f, 0.f, 0.f};
            cu = mfma16(ldfrag(sA, row, 0 * 64 + kg * 16), h8cast(u0), cu);
            cu = mfma16(ldfrag(sA, row, 1 * 64 + kg * 16), h8cast(u1), cu);
            cu = mfma16(ldfrag(sA, row, 2 * 64 + kg * 16), h8cast(u2), cu);
            cu = mfma16(ldfrag(sA, row, 3 * 64 + kg * 16), h8cast(u3), cu);
            if (cl < 8) {
                #pragma unroll
                for (int r = 0; r < 4; ++r)
                    sasd[(w * 16 + kg * 4 + r) * 8 + cl] = cu[r];
            }
        }
        __syncthreads();

        // ---- step 3: masked leaky-relu softmax (lanes 0..39 of each wave) ----
        if (lane < NR * NH) {
            const int i = lane >> 2, h = lane & 3;
            const unsigned mask = kAdj[i];
            const float adv = sasd[(rb + i) * 8 + 4 + h];
            float lg[NR];
            float mx = -1e30f;
            #pragma unroll
            for (int j = 0; j < NR; ++j) {
                float v = adv + sasd[(rb + j) * 8 + h];
                v = (v > 0.f) ? v : 0.2f * v;
                v = ((mask >> j) & 1u) ? v : -1e9f;
                lg[j] = v;
                mx = fmaxf(mx, v);
            }
            float ssum = 0.f;
            #pragma unroll
            for (int j = 0; j < NR; ++j) {
                const float e = __expf(lg[j] - mx);
                lg[j] = e;
                ssum += e;
            }
            const float inv = 0.25f / ssum;   // fold mean-over-heads
            const int base = ((w * 4 + h) * 10 + i) * 12;
            #pragma unroll
            for (int j = 0; j < NR; ++j) sAL[base + j] = lg[j] * inv;
        }
        __syncthreads();

        // ---- step 4: 4 K-chunks: sparse mix_h (36 edges) -> sA ; MFMA, B from L2 ----
        f32x4 C[5] = {};
        #pragma unroll
        for (int h = 0; h < NH; ++h) {
            // mix[i, d] = sum_{j in N(i)} alpha[i,j,h]*nodes[j,d]
            // alpha == 0 exactly for non-edges (exp(-1e9-mx) underflows), so the
            // compile-time-unrolled sparse form is numerically identical.
            #pragma unroll
            for (int i = 0; i < NR; ++i) {
                const float4* ap = (const float4*)&sAL[((w * 4 + h) * 10 + i) * 12];
                const float4 A0 = ap[0], A1 = ap[1], A2 = ap[2];  // A2.z/.w unused
                const float al[NR] = {A0.x, A0.y, A0.z, A0.w, A1.x,
                                      A1.y, A1.z, A1.w, A2.x, A2.y};
                float m0 = 0.f, m1 = 0.f;
                #pragma unroll
                for (int j = 0; j < NR; ++j) {
                    if (kAdjC[i] & (1u << j)) {
                        m0 = fmaf(al[j], ndA[j], m0);
                        m1 = fmaf(al[j], ndB[j], m1);
                    }
                }
                stPair(sA, rb + i, lane, m0, m1);
            }
            __syncthreads();
            // B-frags straight from L2: wave owns out-cols [w*16, w*16+16)
            const char* wb = Wq + ((size_t)((l * 4 + h) * 128 + w * 16 + cl) << 8) + kg * 16;
            const uint4 b0 = *(const uint4*)(wb);
            const uint4 b1 = *(const uint4*)(wb + 64);
            const uint4 b2 = *(const uint4*)(wb + 128);
            const uint4 b3 = *(const uint4*)(wb + 192);
            #pragma unroll
            for (int ks = 0; ks < 4; ++ks) {
                const int kB = ks * 64 + kg * 16;
                const half8 b = h8cast(ks == 0 ? b0 : ks == 1 ? b1 : ks == 2 ? b2 : b3);
                #pragma unroll
                for (int mt = 0; mt < 5; ++mt)
                    C[mt] = mfma16(ldfrag(sA, mt * 16 + cl, kB), b, C[mt]);
            }
            __syncthreads();
        }

        // ---- step 5: epilogue: +bias, GELU, +residual; update sN (+ final store) ----
        const float bg = b_gat[l * HID + w * 16 + cl];
        const int col = w * 16 + cl;
        #pragma unroll
        for (int mt = 0; mt < 5; ++mt) {
            #pragma unroll
            for (int r = 0; r < 4; ++r) {
                const int row = mt * 16 + kg * 4 + r;
                const float v = gelu_exact(C[mt][r] + bg) + sN[row * SNSTR + col];
                sN[row * SNSTR + col] = v;
                if (l == NL - 1) {
                    out_gf[(size_t)(blockIdx.x * G + row / NR) * TOK_FEATS
                           + (row % NR) * HID + col] = v;
                }
            }
        }
        __syncthreads();
    }
}

extern "C" void kernel_launch(void* const* d_in, const int* in_sizes, int n_in,
                              void* d_out, int out_size, void* d_ws, size_t ws_size,
                              hipStream_t stream) {
    const float* x        = (const float*)d_in[0];
    const float* W_enc    = (const float*)d_in[1];
    const float* b_enc    = (const float*)d_in[2];
    const float* g_enc    = (const float*)d_in[3];
    const float* beta_enc = (const float*)d_in[4];
    const float* W_gat    = (const float*)d_in[5];
    const float* att_src  = (const float*)d_in[6];
    const float* att_dst  = (const float*)d_in[7];
    const float* b_gat    = (const float*)d_in[8];

    float* out_gf  = (float*)d_out;
    float* out_enc = (float*)d_out + (size_t)NTOK * TOK_FEATS;
    f16* wsw = (f16*)d_ws;   // 405504 B used

    static bool attr_done = false;
    if (!attr_done) {
        (void)hipFuncSetAttribute((const void*)brain_graph_kernel,
                                  hipFuncAttributeMaxDynamicSharedMemorySize, SMEM_BYTES);
        attr_done = true;
    }

    prep_kernel<<<792, 256, 0, stream>>>(W_gat, att_src, att_dst, wsw);

    brain_graph_kernel<<<NTOK / G, 512, SMEM_BYTES, stream>>>(
        x, W_enc, b_enc, g_enc, beta_enc, b_gat, wsw, out_gf, out_enc);
}

// Round 5
// 397.552 us; speedup vs baseline: 3.5987x; 1.1021x over previous
//
#include <hip/hip_runtime.h>
#include <math.h>

#define NR 10
#define CH 7
#define HID 128
#define NH 4
#define NL 3
#define TOK_FEATS (NR * HID)   // 1280
#define NTOK 16384
#define G 8                    // tokens per block (1 wave each)
#define MROWS (G * NR)         // 80 real A-rows = exactly 5 M-tiles
#define SNSTR 130              // padded fp32 row stride for s_nodes

// LDS layout (bytes): 80000 total -> 2 blocks/CU (16 waves/CU, 50% occ)
#define SN_OFF   0             // float [80][130]        = 41600  (nodes fp32, residual)
#define SA_OFF   41600         // f16   [80][128] swz    = 20480  (A: nodes-f16 / mix chunk)
#define ASD_OFF  62080         // float [80][8]          = 2560   (a_src|a_dst)
#define SAL_OFF  64640         // float [8][4][10][12]   = 15360  (alpha, 0.25-folded)
#define SMEM_BYTES 80000

typedef _Float16 f16;
typedef _Float16 half8 __attribute__((ext_vector_type(8)));
typedef float f32x4 __attribute__((ext_vector_type(4)));

__device__ __forceinline__ float gelu_exact(float x) {
    return 0.5f * x * (1.0f + erff(x * 0.70710678118654752f));
}
__device__ __forceinline__ float rlane(float v, int lane) {
    return __int_as_float(__builtin_amdgcn_readlane(__float_as_int(v), lane));
}
// frag read: 16B at (rc*256 + kByte), XOR-swizzled (G4: kills 256B-stride conflicts)
__device__ __forceinline__ half8 ldfrag(const char* base, int rc, int kByte) {
    return *(const half8*)(base + ((((rc) << 8) + (kByte)) ^ (((rc) & 7) << 4)));
}
// packed f16-pair write: lane owns cols (2*lane, 2*lane+1) of row -> one b32
__device__ __forceinline__ void stPair(char* sA, int row, int lane, float a, float b) {
    const unsigned short ha = __builtin_bit_cast(unsigned short, (f16)a);
    const unsigned short hb = __builtin_bit_cast(unsigned short, (f16)b);
    const unsigned u = ((unsigned)hb << 16) | ha;
    *(unsigned*)(sA + ((((row) << 8) + ((lane) << 2)) ^ (((row) & 7) << 4))) = u;
}
__device__ __forceinline__ half8 h8cast(uint4 u) { return __builtin_bit_cast(half8, u); }
__device__ __forceinline__ f32x4 mfma16(half8 a, half8 b, f32x4 c) {
    return __builtin_amdgcn_mfma_f32_16x16x32_f16(a, b, c, 0, 0, 0);
}

// adjacency bitmasks: bit j of adj[i] == edge j->i (incl self loops)
__device__ __constant__ unsigned short kAdj[NR] = {
    0x01F, 0x0A7, 0x08F, 0x00D, 0x031, 0x072, 0x260, 0x186, 0x180, 0x240
};
// compile-time copy: fully-unrolled sparse mix (36 edges, dead FMAs fold away)
constexpr unsigned kAdjC[NR] = {
    0x01F, 0x0A7, 0x08F, 0x00D, 0x031, 0x072, 0x260, 0x186, 0x180, 0x240
};

// ---------------- prep: W_gat -> Wcat_T fp16 ([l][h][col e][k d], so B-frags are
// contiguous 16B) + U = W @ att_{src,dst} fp16 ([l][c 16][d]; c<4 src, 4..7 dst) ----
__global__ void prep_kernel(const float* __restrict__ W_gat,
                            const float* __restrict__ att_src,
                            const float* __restrict__ att_dst,
                            f16* __restrict__ ws) {
    const int NW = NL * NH * HID * HID;          // 196608
    int t = blockIdx.x * 256 + threadIdx.x;
    if (t < NW) {
        int kk = t & 127, col = (t >> 7) & 127, h = (t >> 14) & 3, l = t >> 16;
        ws[t] = (f16)W_gat[((l * HID + kk) * NH + h) * HID + col];
    } else if (t < NW + NL * 16 * HID) {
        int o = t - NW;
        int d = o & 127, c = (o >> 7) & 15, l = o >> 11;
        float v = 0.f;
        if (c < 8) {
            int h = c & 3;
            const float* att = ((c < 4) ? att_src : att_dst) + (l * NH + h) * HID;
            const float* wr  = W_gat + ((l * HID + d) * NH + h) * HID;
            #pragma unroll 4
            for (int e = 0; e < HID; ++e) v = fmaf(wr[e], att[e], v);
        }
        ws[t] = (f16)v;
    }
}

// ---------------- main kernel: 8 tokens/block, 8 waves, MFMA GAT ----------------
__global__ void
__attribute__((amdgpu_flat_work_group_size(512, 512), amdgpu_waves_per_eu(4, 4)))
brain_graph_kernel(const float* __restrict__ x,
                   const float* __restrict__ W_enc,
                   const float* __restrict__ b_enc,
                   const float* __restrict__ g_enc,
                   const float* __restrict__ beta_enc,
                   const float* __restrict__ b_gat,
                   const f16* __restrict__ wq,
                   float* __restrict__ out_gf,
                   float* __restrict__ out_enc) {
    extern __shared__ __align__(16) char smem[];
    float* sN   = (float*)(smem + SN_OFF);
    char*  sA   = smem + SA_OFF;
    float* sasd = (float*)(smem + ASD_OFF);
    float* sAL  = (float*)(smem + SAL_OFF);

    const int w     = threadIdx.x >> 6;   // wave = token slot (0..7)
    const int lane  = threadIdx.x & 63;
    const int token = blockIdx.x * G + w;
    const int rb    = w * NR;             // this wave's global A-row base
    const int cl    = lane & 15;          // frag row/col-low
    const int kg    = lane >> 4;          // frag k-group

    // ============ encoder: Linear(7->128) + LN + GELU (1 wave / token) ============
    const float xv0 = x[(size_t)token * (NR * CH) + lane];
    const float xv1 = (lane < NR * CH - 64) ? x[(size_t)token * (NR * CH) + 64 + lane] : 0.f;
    {
        const int d0 = lane, d1 = lane + 64;
        #pragma unroll
        for (int r = 0; r < NR; ++r) {
            float a0 = b_enc[r * HID + d0];
            float a1 = b_enc[r * HID + d1];
            #pragma unroll
            for (int c = 0; c < CH; ++c) {
                const int idx = r * CH + c;
                const float xs = (idx < 64) ? rlane(xv0, idx) : rlane(xv1, idx - 64);
                a0 = fmaf(xs, W_enc[idx * HID + d0], a0);
                a1 = fmaf(xs, W_enc[idx * HID + d1], a1);
            }
            float s = a0 + a1, sq = a0 * a0 + a1 * a1;
            #pragma unroll
            for (int off = 32; off > 0; off >>= 1) {
                s  += __shfl_xor(s, off);
                sq += __shfl_xor(sq, off);
            }
            const float mu = s * (1.0f / 128.0f);
            const float rstd = rsqrtf(sq * (1.0f / 128.0f) - mu * mu + 1e-5f);
            const float e0 = gelu_exact((a0 - mu) * rstd * g_enc[r * HID + d0] + beta_enc[r * HID + d0]);
            const float e1 = gelu_exact((a1 - mu) * rstd * g_enc[r * HID + d1] + beta_enc[r * HID + d1]);
            sN[(rb + r) * SNSTR + d0] = e0;
            sN[(rb + r) * SNSTR + d1] = e1;
            out_enc[(size_t)token * TOK_FEATS + r * HID + d0] = e0;
            out_enc[(size_t)token * TOK_FEATS + r * HID + d1] = e1;
        }
    }
    __syncthreads();

    const char* Wq = (const char*)wq;                                  // [l][h][e][d]
    const char* Uq = (const char*)(wq + NL * NH * HID * HID);          // U_T

    for (int l = 0; l < NL; ++l) {
        // ---- prefetch U frags for step 2 (consumed after step-1 barrier) ----
        uint4 u0, u1, u2, u3;
        if (w < 5) {
            const char* ub = Uq + (((l * 16 + cl) * 128 + kg * 8) << 1);
            u0 = *(const uint4*)(ub);
            u1 = *(const uint4*)(ub + 64);
            u2 = *(const uint4*)(ub + 128);
            u3 = *(const uint4*)(ub + 192);
        }

        // ---- step 1: nodes -> regs (col-pairs) + packed nodes-f16 into sA ----
        float ndA[NR], ndB[NR];
        #pragma unroll
        for (int n = 0; n < NR; ++n) {
            const float2 v = *(const float2*)&sN[(rb + n) * SNSTR + 2 * lane];
            ndA[n] = v.x; ndB[n] = v.y;
            stPair(sA, rb + n, lane, v.x, v.y);
        }
        __syncthreads();

        // ---- step 2: a_sd MFMA (waves 0..4, mt=w), B = U_T from L2 ----
        if (w < 5) {
            const int row = w * 16 + cl;
            f32x4 cu = {0.f, 0.f, 0.f, 0.f};
            cu = mfma16(ldfrag(sA, row, 0 * 64 + kg * 16), h8cast(u0), cu);
            cu = mfma16(ldfrag(sA, row, 1 * 64 + kg * 16), h8cast(u1), cu);
            cu = mfma16(ldfrag(sA, row, 2 * 64 + kg * 16), h8cast(u2), cu);
            cu = mfma16(ldfrag(sA, row, 3 * 64 + kg * 16), h8cast(u3), cu);
            if (cl < 8) {
                #pragma unroll
                for (int r = 0; r < 4; ++r)
                    sasd[(w * 16 + kg * 4 + r) * 8 + cl] = cu[r];
            }
        }
        __syncthreads();

        // ---- step 3: masked leaky-relu softmax (lanes 0..39 of each wave) ----
        if (lane < NR * NH) {
            const int i = lane >> 2, h = lane & 3;
            const unsigned mask = kAdj[i];
            const float adv = sasd[(rb + i) * 8 + 4 + h];
            float lg[NR];
            float mx = -1e30f;
            #pragma unroll
            for (int j = 0; j < NR; ++j) {
                float v = adv + sasd[(rb + j) * 8 + h];
                v = (v > 0.f) ? v : 0.2f * v;
                v = ((mask >> j) & 1u) ? v : -1e9f;
                lg[j] = v;
                mx = fmaxf(mx, v);
            }
            float ssum = 0.f;
            #pragma unroll
            for (int j = 0; j < NR; ++j) {
                const float e = __expf(lg[j] - mx);
                lg[j] = e;
                ssum += e;
            }
            const float inv = 0.25f / ssum;   // fold mean-over-heads
            const int base = ((w * 4 + h) * 10 + i) * 12;
            #pragma unroll
            for (int j = 0; j < NR; ++j) sAL[base + j] = lg[j] * inv;
        }
        __syncthreads();

        // ---- step 4: 4 K-chunks: sparse mix_h -> sA ; pipelined B-frags from L2 ----
        f32x4 C[5] = {};
        #pragma unroll
        for (int h = 0; h < NH; ++h) {
            // issue first B-frag load now: its L2 latency hides under the mix FMAs
            const char* wb = Wq + ((size_t)((l * 4 + h) * 128 + w * 16 + cl) << 8) + kg * 16;
            uint4 bcur = *(const uint4*)(wb);
            // mix[i, d] = sum_{j in N(i)} alpha[i,j,h]*nodes[j,d] (sparse, 36 edges;
            // alpha == 0 exactly for non-edges since exp(-1e9-mx) underflows)
            #pragma unroll
            for (int i = 0; i < NR; ++i) {
                const float4* ap = (const float4*)&sAL[((w * 4 + h) * 10 + i) * 12];
                const float4 A0 = ap[0], A1 = ap[1], A2 = ap[2];  // A2.z/.w unused
                const float al[NR] = {A0.x, A0.y, A0.z, A0.w, A1.x,
                                      A1.y, A1.z, A1.w, A2.x, A2.y};
                float m0 = 0.f, m1 = 0.f;
                #pragma unroll
                for (int j = 0; j < NR; ++j) {
                    if (kAdjC[i] & (1u << j)) {
                        m0 = fmaf(al[j], ndA[j], m0);
                        m1 = fmaf(al[j], ndB[j], m1);
                    }
                }
                stPair(sA, rb + i, lane, m0, m1);
            }
            __syncthreads();
            // MFMA over 4 K-frags, B pipelined one-ahead (8 live B regs, not 16)
            #pragma unroll
            for (int ks = 0; ks < 4; ++ks) {
                const half8 b = h8cast(bcur);
                if (ks < 3) bcur = *(const uint4*)(wb + (ks + 1) * 64);
                const int kB = ks * 64 + kg * 16;
                #pragma unroll
                for (int mt = 0; mt < 5; ++mt)
                    C[mt] = mfma16(ldfrag(sA, mt * 16 + cl, kB), b, C[mt]);
            }
            if (h < NH - 1) __syncthreads();   // protect sA before next mix overwrite
        }

        // ---- step 5: +bias, GELU, +residual -> sN only (no partial-line HBM) ----
        const float bg = b_gat[l * HID + w * 16 + cl];
        const int col = w * 16 + cl;
        #pragma unroll
        for (int mt = 0; mt < 5; ++mt) {
            #pragma unroll
            for (int r = 0; r < 4; ++r) {
                const int row = mt * 16 + kg * 4 + r;
                sN[row * SNSTR + col] = gelu_exact(C[mt][r] + bg) + sN[row * SNSTR + col];
            }
        }
        __syncthreads();   // sN complete; also fences sA reads vs next layer's writes
    }

    // ---- final out_gf store: per-token contiguous 256B bursts (like out_enc) ----
    #pragma unroll
    for (int r = 0; r < NR; ++r) {
        out_gf[(size_t)token * TOK_FEATS + r * HID + lane]      = sN[(rb + r) * SNSTR + lane];
        out_gf[(size_t)token * TOK_FEATS + r * HID + 64 + lane] = sN[(rb + r) * SNSTR + 64 + lane];
    }
}

extern "C" void kernel_launch(void* const* d_in, const int* in_sizes, int n_in,
                              void* d_out, int out_size, void* d_ws, size_t ws_size,
                              hipStream_t stream) {
    const float* x        = (const float*)d_in[0];
    const float* W_enc    = (const float*)d_in[1];
    const float* b_enc    = (const float*)d_in[2];
    const float* g_enc    = (const float*)d_in[3];
    const float* beta_enc = (const float*)d_in[4];
    const float* W_gat    = (const float*)d_in[5];
    const float* att_src  = (const float*)d_in[6];
    const float* att_dst  = (const float*)d_in[7];
    const float* b_gat    = (const float*)d_in[8];

    float* out_gf  = (float*)d_out;
    float* out_enc = (float*)d_out + (size_t)NTOK * TOK_FEATS;
    f16* wsw = (f16*)d_ws;   // 405504 B used

    static bool attr_done = false;
    if (!attr_done) {
        (void)hipFuncSetAttribute((const void*)brain_graph_kernel,
                                  hipFuncAttributeMaxDynamicSharedMemorySize, SMEM_BYTES);
        attr_done = true;
    }

    prep_kernel<<<792, 256, 0, stream>>>(W_gat, att_src, att_dst, wsw);

    brain_graph_kernel<<<NTOK / G, 512, SMEM_BYTES, stream>>>(
        x, W_enc, b_enc, g_enc, beta_enc, b_gat, wsw, out_gf, out_enc);
}